// Round 9
// baseline (133.879 us; speedup 1.0000x reference)
//
#include <hip/hip_runtime.h>
#include <math.h>

// KTVLoss: inputs out_l, out_r, input_i : (8,3,512,512) fp32. Output: 1 fp32 scalar.
//
// Sx = 10x10 box sum of |dI/dh| (502x503), Sy = box sum of |dI/dw| (503x502).
// Reference pairs them by FLAT index: Sx(i,j) with Sy(i,i+j) if i+j<502 else
// Sy(i+1,i+j-502). ratio = (SxL+SyL+SxR+SyR)/(SxI+SyI+1e-4), mean over 24*502*503.
// grad part (fp32): mean|GxL+GxR-GxI| + mean|GyL+GyR-GyI| over 24*511*512 each.
// norm part carries 1e-4 weight -> packed f16 (abs err ~1e-5; validated R4-R9).
//
// R19: R17/R18 established VALU-issue-bound (occupancy->VALUBusy 70%; instr
// cut -> time cut). Two composing levers left: (a) 4th block/CU (needs LDS
// <=40KB and >=1024 blocks), (b) staging instruction overhead. This round:
//  - ALL-REGISTER row streaming: no LDS row ring, no global_load_lds. Each
//    thread loads its 6 row values (L,R,I x cols j,j+1) into a 2-deep reg
//    queue: issue row s+2 at step s (6 loads, one shared voffset + saddr,
//    neighbor via clamped voffset), retire via the counted vmcnt(6) barrier
//    of step s+1, consume at s+2 -- same cadence proof as the gload path.
//    Kills 3 ds_read2 + 3 gload_lds + pad machinery (~-8 instr/step net).
//  - LDS -> 16.4KB (syring + awin + red). RB=12: 42 bands x 24 = 1008 blocks
//    ~= 4/CU; __launch_bounds__(512,8) = 8 waves/SIMD, VGPR cap 64.
//  - Lag-algebra fix: R15-R18's snap2 double-delay paired Sx row s-13 with
//    Sy s-12 (1 late vs validated R13 algebra; masked by the 1e-4 weight).
//    Ratio now reads snap1 directly (set at patch s-1 = Sx row s-12 = u).
// Schedule invariants kept: LDS reads at top, loads mid, LDS writes aged
// before the lgkm(0) drain, counted vmcnt (never 0), clamp-dup tail cadence.
//
// VGPR cap law: cap = 512/min_waves_per_EU; (512,8) -> 64. Watch for spill
// (symptom: WRITE_SIZE >> 30 KB). Fallback: RB=16 + (512,6).

namespace {

constexpr int H = 512, W = 512;
constexpr int CX = W - 10 + 1;   // 503 Sx cols (Sy has 503 rows)
constexpr int CY = W - 10;       // 502 Sy cols
constexpr int RB = 12;           // Sx rows per band
constexpr int NBANDS = (CY + RB - 1) / RB;   // 42
constexpr int NIMG = 24;
constexpr int NBLOCKS = NIMG * NBANDS;       // 1008 ~= 4 per CU

constexpr int SMAX = RB + 9;     // last scan row offset (21)
constexpr int NSTEP = RB + 12;   // supersteps (24 = 6x4): ratios end at s=23

constexpr int HW1 = H * W - 1;   // in-image clamp for the +1 neighbor load

typedef __fp16 h2 __attribute__((ext_vector_type(2)));

__device__ __forceinline__ int h2i(h2 v) { int r; __builtin_memcpy(&r, &v, 4); return r; }
__device__ __forceinline__ h2 i2h(int v) { h2 r; __builtin_memcpy(&r, &v, 4); return r; }

template <int C, int RM>
__device__ __forceinline__ int dppmov(int v) {
  return __builtin_amdgcn_update_dpp(0, v, C, RM, 0xf, true);
}
// full 64-lane inclusive prefix sum of a f16x2 pack (pure VALU)
__device__ __forceinline__ h2 scan64(h2 v) {
  v += i2h(dppmov<0x111, 0xf>(h2i(v)));  // row_shr:1
  v += i2h(dppmov<0x112, 0xf>(h2i(v)));  // row_shr:2
  v += i2h(dppmov<0x114, 0xf>(h2i(v)));  // row_shr:4
  v += i2h(dppmov<0x118, 0xf>(h2i(v)));  // row_shr:8
  v += i2h(dppmov<0x142, 0xa>(h2i(v)));  // row_bcast15 -> rows 1,3
  v += i2h(dppmov<0x143, 0xc>(h2i(v)));  // row_bcast31 -> rows 2,3
  return v;
}

// barrier with COUNTED vmcnt(6): lgkmcnt(0) for LDS visibility; the current
// step's 6 register loads stay in flight across the barrier (never 0).
// Loads of step s are retired by the barrier of step s+1 (6 newer loads
// issued), before their values are consumed at step s+2.
// encoding: vmcnt[3:0]=6, exp[6:4]=7(max), lgkm[11:8]=0.
__device__ __forceinline__ void kbarrier_vm() {
  __builtin_amdgcn_sched_barrier(0);
  __builtin_amdgcn_s_waitcnt(0x0076);
  __builtin_amdgcn_s_barrier();
  __builtin_amdgcn_sched_barrier(0);
}

}  // namespace

__global__ __launch_bounds__(512, 8) void ktv_main(const float* __restrict__ L,
                                                   const float* __restrict__ R,
                                                   const float* __restrict__ I,
                                                   double* __restrict__ partial) {
  const int blk = blockIdx.x;
  const int img = blk / NBANDS;
  const int band = blk % NBANDS;
  const int i0 = band * RB;
  const int j = threadIdx.x;  // column
  const int lane = j & 63;
  const int wv = j >> 6;
  const int wtop = (wv + 1) << 6;               // awin slot holding own wave's total
  const bool patch = (lane >= 55) && (wv < 7);  // window crosses into next wave

  const bool lastb = (band == NBANDS - 1);
  const int gyEnd = lastb ? H : (i0 + RB);        // Gy rows owned: [i0, gyEnd)
  const int gxEnd = lastb ? (H - 1) : (i0 + RB);  // Gx rows owned: [i0, gxEnd)
  const int sxEnd = lastb ? CY : (i0 + RB);       // Sx rows owned: [i0, sxEnd)

  const size_t base = (size_t)img * (H * W);
  const float* pL = L + base;
  const float* pR = R + base;
  const float* pI = I + base;

  __shared__ int syring[4 * CY];      // completed Sy rows (f16x2 n,d), depth-4 ring
  __shared__ int2 awin[2 * 522];      // prefix packs [parity][col]
                                      // col k = prefix through col k-1; [64w]=T_{w-1}
  __shared__ float redN[8], redG[8];

  // hist as a 10-deep shift-register queue (registers; constant-index shift;
  // unroll_count(4) coalesces the per-copy shifts)
  h2 hqY[10], hqX[10];
#pragma unroll
  for (int t = 0; t < 10; ++t) { hqY[t] = (h2)(__fp16)0; hqX[t] = (h2)(__fp16)0; }
  h2 runY = (h2)(__fp16)0, runX = (h2)(__fp16)0;
  h2 snap1 = (h2)(__fp16)0;
  float accN = 0.f, accG = 0.f;
  float prevL = 0.f, prevR = 0.f, prevI = 0.f;

  // prologue: rows i0 (queue a, ready by first use) and i0+1 (queue b, in
  // flight). Rows <= i0+1 <= 493 -> no clamps needed; j=511 neighbor reads
  // next row's col 0 (in-bounds, garbage-but-guarded).
  const int g0 = i0 * W + j;
  float aL = pL[g0], aR = pR[g0], aI = pI[g0];
  float aNL = pL[g0 + 1], aNR = pR[g0 + 1], aNI = pI[g0 + 1];
  __builtin_amdgcn_sched_barrier(0);
  const int g1 = g0 + W;
  float bL = pL[g1], bR = pR[g1], bI = pI[g1];
  float bNL = pL[g1 + 1], bNR = pR[g1 + 1], bNI = pI[g1 + 1];
  __builtin_amdgcn_sched_barrier(0);

  // NSTEP 1-row supersteps: scan s=0..21, patch (row s-1) s=1..22, ratio s=12..23
#pragma clang loop unroll_count(4)
  for (int s = 0; s < NSTEP; ++s) {
    const bool doScan = (s <= SMAX);
    const bool doPatch = (s >= 1) && (s <= SMAX + 1);
    const bool doRatio = (s >= 12);
    const int aWr = (s & 1) * 522;   // awin write parity base
    const int aRd = aWr ^ 522;       // awin read parity base (written at s-1)

    // ---- top: syring read for ratio Sx row s-12 ----
    int syrd = 0;
    bool uok = false;
    if (doRatio) {
      const int u = i0 + s - 12;
      if (u < sxEnd && j < CX) {
        int jy = u + j, rw = u;
        if (jy >= CY) { jy -= CY; ++rw; }
        syrd = syring[(rw & 3) * CY + jy];
        uok = true;
      }
    }

    // ---- top: awin prefix reads for patch row s-1 (written at s-1) ----
    int2 w0 = make_int2(0, 0), w10 = w0, wT = w0;
    if (doPatch) {
      w0 = awin[aRd + j];
      w10 = awin[aRd + j + 10];
      wT = awin[aRd + wtop];
    }

    // ---- consume queue a = row s (loaded at step s-2, barrier-retired) ----
    const float xVL = aL, xVR = aR, xVI = aI;
    const float xNL = aNL, xNR = aNR, xNI = aNI;

    // ---- issue row s+2 (clamp-dup at tail keeps 6-load vmcnt cadence) ----
    int srow = s + 2; if (srow > SMAX) srow = SMAX;  // dup re-reads same row
    int grow = i0 + srow; if (grow > H - 1) grow = H - 1;  // lastb clamp
    const int gg = grow * W + j;
    int ggn = gg + 1; if (ggn > HW1) ggn = HW1;  // stay in-image (j=511 guarded)
    const float cL = pL[gg], cR = pR[gg], cI = pI[gg];
    const float cNL = pL[ggn], cNR = pR[ggn], cNI = pI[ggn];

    // ---- scan row s: gradients, packs, DPP scan -> awin write (aged) ----
    if (doScan) {
      const int r = i0 + s;
      const float gyl = xNL - xVL, gyr = xNR - xVR, gyi = xNI - xVI;
      const float gxl = xVL - prevL, gxr = xVR - prevR, gxi = xVI - prevI;
      prevL = xVL; prevR = xVR; prevI = xVI;
      if (r < gyEnd && j < W - 1) accG += fabsf(gyl + gyr - gyi);
      if (s > 0 && (r - 1) < gxEnd) accG += fabsf(gxl + gxr - gxi);
      float yn = fabsf(gyl) + fabsf(gyr), yd = fabsf(gyi);
      float xn = fabsf(gxl) + fabsf(gxr), xd = fabsf(gxi);
      if (j == W - 1) { yn = 0.f; yd = 0.f; }
      if (r >= H) { yn = 0.f; yd = 0.f; xn = 0.f; xd = 0.f; }
      const h2 Y = __builtin_amdgcn_cvt_pkrtz(yn, yd);
      h2 X = (h2)(__fp16)0;
      if (s != 0) X = __builtin_amdgcn_cvt_pkrtz(xn, xd);
      const h2 AY = scan64(Y), AX = scan64(X);
      awin[aWr + j + 1] = make_int2(h2i(AY), h2i(AX));
    }

    // ---- ratio finish: snap1 (set at patch of step s-1) = Sx row s-12 = u ----
    if (uok) {
      const h2 sy = i2h(syrd);
      const float num = (float)snap1.x + (float)sy.x;
      const float den = (float)snap1.y + (float)sy.y + 1e-4f;
      accN += num * __builtin_amdgcn_rcpf(den);
    }

    // ---- patch row s-1: window combine, vertical ring, syring write ----
    if (doPatch) {
      h2 hh = i2h(w10.x), hx = i2h(w10.y);
      if (lane != 0) { hh -= i2h(w0.x); hx -= i2h(w0.y); }
      if (patch) { hh += i2h(wT.x); hx += i2h(wT.y); }
      runY += hh - hqY[0]; runX += hx - hqX[0];
      snap1 = runX;  // Sx row s-11; consumed at ratio of step s+1 (u = s+1-12)
      {
        const int iY = i0 + s - 10;  // Sy row s-10 complete
        if (s >= 10 && iY <= sxEnd && j < CY) syring[(iY & 3) * CY + j] = h2i(runY);
      }
      // queue: shift by 1, insert the new window value
#pragma unroll
      for (int k = 0; k < 9; ++k) { hqY[k] = hqY[k + 1]; hqX[k] = hqX[k + 1]; }
      hqY[9] = hh; hqX[9] = hx;
    }

    // ---- rotate register row queues ----
    aL = bL; aR = bR; aI = bI; aNL = bNL; aNR = bNR; aNI = bNI;
    bL = cL; bR = cR; bI = cI; bNL = cNL; bNR = cNR; bNI = cNI;

    kbarrier_vm();
  }

  // block reduction (2 channels)
#pragma unroll
  for (int o2 = 32; o2 > 0; o2 >>= 1) {
    accN += __shfl_down(accN, o2);
    accG += __shfl_down(accG, o2);
  }
  if (lane == 0) { redN[wv] = accN; redG[wv] = accG; }
  __syncthreads();
  if (j == 0) {
    float n = 0.f, g = 0.f;
#pragma unroll
    for (int w2 = 0; w2 < 8; ++w2) { n += redN[w2]; g += redG[w2]; }
    double* p = partial + (size_t)blk * 2;
    p[0] = (double)n; p[1] = (double)g;
  }
}

__global__ __launch_bounds__(64) void ktv_reduce(const double* __restrict__ partial,
                                                 float* __restrict__ out) {
  double n = 0.0, g = 0.0;
  for (int i = threadIdx.x; i < NBLOCKS; i += 64) {
    const double* p = partial + (size_t)i * 2;
    n += p[0]; g += p[1];
  }
#pragma unroll
  for (int o2 = 32; o2 > 0; o2 >>= 1) {
    n += __shfl_down(n, o2);
    g += __shfl_down(g, o2);
  }
  if (threadIdx.x == 0) {
    const double norm_loss = n / 6060144.0;  // 24*502*503
    const double grad_loss = g / 6279168.0;  // 24*511*512 (gx and gy share denom)
    out[0] = (float)(1e-4 * norm_loss + grad_loss);
  }
}

extern "C" void kernel_launch(void* const* d_in, const int* in_sizes, int n_in,
                              void* d_out, int out_size, void* d_ws, size_t ws_size,
                              hipStream_t stream) {
  (void)in_sizes; (void)n_in; (void)out_size; (void)ws_size;
  const float* L = (const float*)d_in[0];
  const float* R = (const float*)d_in[1];
  const float* I = (const float*)d_in[2];
  double* partial = (double*)d_ws;  // NBLOCKS*2 doubles = 16128 B
  float* out = (float*)d_out;

  hipLaunchKernelGGL(ktv_main, dim3(NBLOCKS), dim3(512), 0, stream, L, R, I, partial);
  hipLaunchKernelGGL(ktv_reduce, dim3(1), dim3(64), 0, stream, partial, out);
}